// Round 12
// baseline (160.289 us; speedup 1.0000x reference)
//
#include <hip/hip_runtime.h>
#include <hip/hip_bf16.h>

#define B_    128
#define N_    196
#define HDIM  512
#define VDIM  2048
#define ATT   512
#define M_TOT (B_ * N_)   // 25088

#define BKK 64             // K step (64 bf16 = 128B = 8 chunks of 16B)
#define NT  (VDIM / BKK)   // 32 K-steps
#define BM1 128
#define BN1 128
#define N8     ((B_ * N_ * VDIM) / 8)   // 6,422,528 float8 items
#define NCONVB 3136                      // conv blocks; 8 unrolled iters each

typedef float  f32x4  __attribute__((ext_vector_type(4)));
typedef __bf16 bf16x8 __attribute__((ext_vector_type(8)));

__device__ __forceinline__ void gload_lds16(const void* g, void* l) {
    __builtin_amdgcn_global_load_lds(
        (const __attribute__((address_space(1))) void*)g,
        (__attribute__((address_space(3))) void*)l, 16, 0, 0);
}

__device__ __forceinline__ float fast_tanh(float x) {
    float ax = fabsf(x);
    float e  = __expf(-2.f * ax);          // in (0,1], no overflow
    float t  = (1.f - e) / (1.f + e);
    return copysignf(t, x);
}

// ---------------------------------------------------------------------------
// Kernel CP (merged):
//   [0,128):           whp = h@Ww + Wb + Ub   (unroll-8, 16 loads in flight)
//   [128,384):         Uw transpose -> UwT bf16
//   [384,384+NCONVB):  V fp32 -> bf16, FULLY UNROLLED x8 (compile-time
//                      stride -> 16 loads in flight -> HBM-BW-bound)
// ---------------------------------------------------------------------------
__global__ void k_convprep(const float* __restrict__ V, __bf16* __restrict__ Vb,
                           const float* __restrict__ Uw, __bf16* __restrict__ UwT,
                           const float* __restrict__ h, const float* __restrict__ Ww,
                           const float* __restrict__ Wb, const float* __restrict__ Ub,
                           float* __restrict__ whp) {
    int t = threadIdx.x;  // 256
    if (blockIdx.x < 128) {
        __shared__ float hs[HDIM];
        int b = blockIdx.x;
        hs[t]       = h[(size_t)b * HDIM + t];
        hs[t + 256] = h[(size_t)b * HDIM + t + 256];
        __syncthreads();
        float a0[8] = {0,0,0,0,0,0,0,0}, a1[8] = {0,0,0,0,0,0,0,0};
        for (int k0 = 0; k0 < HDIM; k0 += 8) {
#pragma unroll
            for (int u = 0; u < 8; ++u) {
                float hv = hs[k0 + u];
                a0[u] += hv * Ww[(size_t)(k0 + u) * ATT + t];
                a1[u] += hv * Ww[(size_t)(k0 + u) * ATT + t + 256];
            }
        }
        float s0 = ((a0[0] + a0[1]) + (a0[2] + a0[3])) + ((a0[4] + a0[5]) + (a0[6] + a0[7]));
        float s1 = ((a1[0] + a1[1]) + (a1[2] + a1[3])) + ((a1[4] + a1[5]) + (a1[6] + a1[7]));
        whp[(size_t)b * ATT + t]       = s0 + Wb[t] + Ub[t];
        whp[(size_t)b * ATT + t + 256] = s1 + Wb[t + 256] + Ub[t + 256];
    } else if (blockIdx.x < 384) {
        __shared__ __bf16 st[64][65];
        int bb = blockIdx.x - 128;
        int k0 = (bb & 31) * 64;
        int c0 = (bb >> 5) * 64;
#pragma unroll
        for (int i = 0; i < 16; ++i) {
            int lin = i * 256 + t;
            int kk = lin >> 6, cc = lin & 63;
            st[kk][cc] = (__bf16)Uw[(size_t)(k0 + kk) * ATT + c0 + cc];
        }
        __syncthreads();
#pragma unroll
        for (int i = 0; i < 16; ++i) {
            int lin = i * 256 + t;
            int cc = lin >> 6, kk = lin & 63;
            UwT[(size_t)(c0 + cc) * VDIM + k0 + kk] = st[kk][cc];
        }
    } else {
        // conv: compile-time stride -> full unroll, all 16 loads in flight
        size_t base = (size_t)(blockIdx.x - 384) * 256 + t;   // < 802816
        const float4* Vp = reinterpret_cast<const float4*>(V);
        float4 xs[8], ys[8];
#pragma unroll
        for (int u = 0; u < 8; ++u) {
            size_t i = base + (size_t)u * (NCONVB * 256);
            xs[u] = Vp[2 * i];
            ys[u] = Vp[2 * i + 1];
        }
#pragma unroll
        for (int u = 0; u < 8; ++u) {
            size_t i = base + (size_t)u * (NCONVB * 256);
            float4 x = xs[u], y = ys[u];
            bf16x8 w;
            w[0] = (__bf16)x.x; w[1] = (__bf16)x.y; w[2] = (__bf16)x.z; w[3] = (__bf16)x.w;
            w[4] = (__bf16)y.x; w[5] = (__bf16)y.y; w[6] = (__bf16)y.z; w[7] = (__bf16)y.w;
            reinterpret_cast<bf16x8*>(Vb)[i] = w;
        }
    }
}

// ---------------------------------------------------------------------------
// Kernel G (main): 128x128 tile, BK=64, 4 waves, counted-vmcnt depth-2
// pipeline, XOR-swizzled gload_lds both operands. [R7/R10/R11-verified]
// ---------------------------------------------------------------------------
__global__ __launch_bounds__(256, 2) void k_scores128(
    const __bf16* __restrict__ Vb, const __bf16* __restrict__ UwT,
    const float* __restrict__ whp, const float* __restrict__ vw,
    float* __restrict__ e_part)
{
    __shared__ __align__(16) __bf16 As[2][BM1][BKK];   // 32 KB
    __shared__ __align__(16) __bf16 Bs[2][BN1][BKK];   // 32 KB
    __shared__ float red[2][BM1];

    int bid = blockIdx.x;
    int lid = (bid & 7) * (784 / 8) + (bid >> 3);
    int mtile = lid >> 2;         // 0..195
    int cc    = lid & 3;          // 0..3
    int m0 = mtile * BM1;
    int c0 = cc * BN1;
    int t    = threadIdx.x;
    int lane = t & 63;
    int wave = t >> 6;
    int wr = wave >> 1;
    int wc = wave & 1;

    f32x4 acc[4][4];
#pragma unroll
    for (int i = 0; i < 4; ++i)
#pragma unroll
        for (int j = 0; j < 4; ++j) acc[i][j] = (f32x4){0.f, 0.f, 0.f, 0.f};

    int lr  = lane >> 3;
    int csw = ((lane & 7) ^ lr) * 8;
    const __bf16* AgS = Vb  + (size_t)(m0 + wave * 32 + lr) * VDIM + csw;
    const __bf16* BgS = UwT + (size_t)(c0 + wave * 32 + lr) * VDIM + csw;
    __bf16* Al0 = &As[0][wave * 32 + lr][(lane & 7) * 8];
    __bf16* Bl0 = &Bs[0][wave * 32 + lr][(lane & 7) * 8];

#define STAGE(buf, kt)                                                          \
    do {                                                                        \
        _Pragma("unroll")                                                       \
        for (int i = 0; i < 4; ++i) {                                           \
            gload_lds16(AgS + (kt) * BKK + (size_t)i * 8 * VDIM,                \
                        Al0 + (buf) * (BM1 * BKK) + i * 8 * BKK);               \
            gload_lds16(BgS + (kt) * BKK + (size_t)i * 8 * VDIM,                \
                        Bl0 + (buf) * (BN1 * BKK) + i * 8 * BKK);               \
        }                                                                       \
    } while (0)

    int lcol = lane & 15;
    int lg4  = lane >> 4;
    int arow0 = wr * 64;
    int bcol0 = wc * 64;

    STAGE(0, 0);
    __builtin_amdgcn_sched_barrier(0);   // pin issue order: tile0 before tile1
    STAGE(1, 1);

    for (int kt = 0; kt < NT; ++kt) {
        int buf = kt & 1;
        if (kt < NT - 1) {
            asm volatile("s_waitcnt vmcnt(8)\n\ts_barrier" ::: "memory");
        } else {
            asm volatile("s_waitcnt vmcnt(0)\n\ts_barrier" ::: "memory");
        }
        __builtin_amdgcn_sched_barrier(0);

#pragma unroll
        for (int ks = 0; ks < 2; ++ks) {
            bf16x8 af[4], bfr[4];
#pragma unroll
            for (int i = 0; i < 4; ++i) {
                int row = arow0 + i * 16 + lcol;
                int ch  = ((ks * 4 + lg4) ^ (row & 7)) * 8;
                af[i] = *reinterpret_cast<const bf16x8*>(&As[buf][row][ch]);
            }
#pragma unroll
            for (int j = 0; j < 4; ++j) {
                int row = bcol0 + j * 16 + lcol;
                int ch  = ((ks * 4 + lg4) ^ (row & 7)) * 8;
                bfr[j] = *reinterpret_cast<const bf16x8*>(&Bs[buf][row][ch]);
            }
            __builtin_amdgcn_s_setprio(1);
#pragma unroll
            for (int i = 0; i < 4; ++i)
#pragma unroll
                for (int j = 0; j < 4; ++j)
                    acc[i][j] = __builtin_amdgcn_mfma_f32_16x16x32_bf16(af[i], bfr[j], acc[i][j], 0, 0, 0);
            __builtin_amdgcn_s_setprio(0);
        }

        __builtin_amdgcn_sched_barrier(0);
        asm volatile("s_barrier" ::: "memory");   // buf free: all waves consumed it
        if (kt + 2 < NT) STAGE(buf, kt + 2);
    }
#undef STAGE

    // ---- epilogue: rowsum over this block's 128 cols ----
    int lrow4 = lg4 * 4;
#pragma unroll
    for (int i = 0; i < 4; ++i) {
        float rs[4] = {0.f, 0.f, 0.f, 0.f};
#pragma unroll
        for (int j = 0; j < 4; ++j) {
            int col = c0 + wc * 64 + j * 16 + lcol;
            float vwv = vw[col];
#pragma unroll
            for (int r = 0; r < 4; ++r) {
                int m = m0 + wr * 64 + i * 16 + lrow4 + r;
                int b = m / N_;
                float x = acc[i][j][r] + whp[(size_t)b * ATT + col];
                rs[r] += fast_tanh(x) * vwv;
            }
        }
#pragma unroll
        for (int r = 0; r < 4; ++r) {
            float v = rs[r];
            v += __shfl_xor(v, 1);
            v += __shfl_xor(v, 2);
            v += __shfl_xor(v, 4);
            v += __shfl_xor(v, 8);
            if (lcol == 0)
                red[wc][wr * 64 + i * 16 + lrow4 + r] = v;
        }
    }
    __syncthreads();
    if (t < BM1)
        e_part[(size_t)cc * M_TOT + m0 + t] = red[0][t] + red[1][t];
}

// ---------------------------------------------------------------------------
// Kernel G (fallback, no-ws path): 128x128, fp32 A reg-staged (R3-proven).
// ---------------------------------------------------------------------------
__global__ __launch_bounds__(256, 2) void k_scores_small(
    const float* __restrict__ Vf, const __bf16* __restrict__ UwT,
    const float* __restrict__ whp, const float* __restrict__ vw,
    float* __restrict__ e_part)
{
    __shared__ __align__(16) __bf16 As[2][BM1][BKK];
    __shared__ __align__(16) __bf16 Bs[2][BN1][BKK];
    __shared__ float red[2][BM1];

    int bid = blockIdx.x;
    int lid = (bid & 7) * (784 / 8) + (bid >> 3);
    int mtile = lid >> 2;
    int cc    = lid & 3;
    int m0 = mtile * BM1;
    int c0 = cc * BN1;
    int t    = threadIdx.x;
    int lane = t & 63;
    int wave = t >> 6;
    int wr = wave >> 1;
    int wc = wave & 1;

    f32x4 acc[4][4];
#pragma unroll
    for (int i = 0; i < 4; ++i)
#pragma unroll
        for (int j = 0; j < 4; ++j) acc[i][j] = (f32x4){0.f, 0.f, 0.f, 0.f};

    int lr  = lane >> 3;
    int csw = ((lane & 7) ^ lr) * 8;
    const __bf16* BgS = UwT + (size_t)(c0 + wave * 32 + lr) * VDIM + csw;
    __bf16* Bl0 = &Bs[0][wave * 32 + lr][(lane & 7) * 8];

    int ra = t >> 1;
    int ka = (t & 1) * 32;
    const float* Af = Vf + (size_t)(m0 + ra) * VDIM + ka;

#define STAGE1(buf, kt)                                                         \
    do {                                                                        \
        _Pragma("unroll")                                                       \
        for (int i = 0; i < 4; ++i)                                             \
            gload_lds16(BgS + (kt) * BKK + (size_t)i * 8 * VDIM,                \
                        Bl0 + (buf) * (BN1 * BKK) + i * 8 * BKK);               \
        const float4* src = reinterpret_cast<const float4*>(Af + (kt) * BKK);   \
        _Pragma("unroll")                                                       \
        for (int i = 0; i < 4; ++i) {                                           \
            float4 x = src[2 * i];                                              \
            float4 y = src[2 * i + 1];                                          \
            bf16x8 w;                                                           \
            w[0] = (__bf16)x.x; w[1] = (__bf16)x.y;                             \
            w[2] = (__bf16)x.z; w[3] = (__bf16)x.w;                             \
            w[4] = (__bf16)y.x; w[5] = (__bf16)y.y;                             \
            w[6] = (__bf16)y.z; w[7] = (__bf16)y.w;                             \
            int ch = (((t & 1) * 4 + i) ^ (ra & 7)) * 8;                        \
            *reinterpret_cast<bf16x8*>(&As[buf][ra][ch]) = w;                   \
        }                                                                       \
    } while (0)

    int lcol = lane & 15;
    int lg4  = lane >> 4;
    int arow0 = wr * 64;
    int bcol0 = wc * 64;

    STAGE1(0, 0);
    __syncthreads();

    for (int kt = 0; kt < NT; ++kt) {
        int buf = kt & 1;
        if (kt + 1 < NT) STAGE1(buf ^ 1, kt + 1);
#pragma unroll
        for (int ks = 0; ks < 2; ++ks) {
            bf16x8 af[4], bfr[4];
#pragma unroll
            for (int i = 0; i < 4; ++i) {
                int row = arow0 + i * 16 + lcol;
                int ch  = ((ks * 4 + lg4) ^ (row & 7)) * 8;
                af[i] = *reinterpret_cast<const bf16x8*>(&As[buf][row][ch]);
            }
#pragma unroll
            for (int j = 0; j < 4; ++j) {
                int row = bcol0 + j * 16 + lcol;
                int ch  = ((ks * 4 + lg4) ^ (row & 7)) * 8;
                bfr[j] = *reinterpret_cast<const bf16x8*>(&Bs[buf][row][ch]);
            }
#pragma unroll
            for (int i = 0; i < 4; ++i)
#pragma unroll
                for (int j = 0; j < 4; ++j)
                    acc[i][j] = __builtin_amdgcn_mfma_f32_16x16x32_bf16(af[i], bfr[j], acc[i][j], 0, 0, 0);
        }
        __syncthreads();
    }
#undef STAGE1

    int lrow4 = lg4 * 4;
#pragma unroll
    for (int i = 0; i < 4; ++i) {
        float rs[4] = {0.f, 0.f, 0.f, 0.f};
#pragma unroll
        for (int j = 0; j < 4; ++j) {
            int col = c0 + wc * 64 + j * 16 + lcol;
            float vwv = vw[col];
#pragma unroll
            for (int r = 0; r < 4; ++r) {
                int m = m0 + wr * 64 + i * 16 + lrow4 + r;
                int b = m / N_;
                float x = acc[i][j][r] + whp[(size_t)b * ATT + col];
                rs[r] += fast_tanh(x) * vwv;
            }
        }
#pragma unroll
        for (int r = 0; r < 4; ++r) {
            float v = rs[r];
            v += __shfl_xor(v, 1);
            v += __shfl_xor(v, 2);
            v += __shfl_xor(v, 4);
            v += __shfl_xor(v, 8);
            if (lcol == 0)
                red[wc][wr * 64 + i * 16 + lrow4 + r] = v;
        }
    }
    __syncthreads();
    if (t < BM1)
        e_part[(size_t)cc * M_TOT + m0 + t] = red[0][t] + red[1][t];
}

// ---------------------------------------------------------------------------
// Kernel CS (fused softmax + ctx, bf16 V): each (b,ch) block recomputes the
// softmax over N=196 from the 4 e-partials (identical fp ops -> identical a
// in both ch blocks, deterministic); ch==0 writes a_out; both accumulate ctx.
// ---------------------------------------------------------------------------
__global__ void k_ctx_sm(const __bf16* __restrict__ Vb, const float* __restrict__ e_part,
                         const float* __restrict__ vb, float* __restrict__ a_out,
                         float* __restrict__ ctx) {
    int b  = blockIdx.x;   // 128
    int ch = blockIdx.y;   // 2 chunks of 1024 cols
    int t  = threadIdx.x;  // 128
    __shared__ float sm[128];
    __shared__ float as_[N_];

    int n0 = t, n1 = t + 128;
    float ev0 = 0.f, ev1 = 0.f, e0 = -1e30f, e1 = -1e30f;
    {
        int m = b * N_ + n0;
        ev0 = e_part[m] + e_part[M_TOT + m] + e_part[2 * M_TOT + m] + e_part[3 * M_TOT + m] + vb[0];
        e0 = ev0;
    }
    if (n1 < N_) {
        int m = b * N_ + n1;
        ev1 = e_part[m] + e_part[M_TOT + m] + e_part[2 * M_TOT + m] + e_part[3 * M_TOT + m] + vb[0];
        e1 = ev1;
    }
    sm[t] = fmaxf(e0, e1);
    __syncthreads();
    for (int s = 64; s > 0; s >>= 1) {
        if (t < s) sm[t] = fmaxf(sm[t], sm[t + s]);
        __syncthreads();
    }
    float mx = sm[0];
    __syncthreads();
    float x0 = __expf(ev0 - mx);
    float x1 = (n1 < N_) ? __expf(ev1 - mx) : 0.f;
    sm[t] = x0 + x1;
    __syncthreads();
    for (int s = 64; s > 0; s >>= 1) {
        if (t < s) sm[t] += sm[t + s];
        __syncthreads();
    }
    float inv = 1.f / sm[0];
    as_[n0] = x0 * inv;
    if (n1 < N_) as_[n1] = x1 * inv;
    if (ch == 0) {
        a_out[(size_t)b * N_ + n0] = x0 * inv;
        if (n1 < N_) a_out[(size_t)b * N_ + n1] = x1 * inv;
    }
    __syncthreads();

    int col = ch * 1024 + t * 8;
    const __bf16* Vp = Vb + (size_t)b * N_ * VDIM + col;
    float av[8] = {0.f, 0.f, 0.f, 0.f, 0.f, 0.f, 0.f, 0.f};
#pragma unroll 4
    for (int n = 0; n < N_; ++n) {
        bf16x8 v = *reinterpret_cast<const bf16x8*>(Vp + (size_t)n * VDIM);
        float an = as_[n];
#pragma unroll
        for (int j = 0; j < 8; ++j) av[j] += an * (float)v[j];
    }
    f32x4 lo = {av[0], av[1], av[2], av[3]};
    f32x4 hi = {av[4], av[5], av[6], av[7]};
    f32x4* dst = reinterpret_cast<f32x4*>(ctx + (size_t)b * VDIM + col);
    dst[0] = lo;
    dst[1] = hi;
}

// ---------------------------------------------------------------------------
// Fallback softmax + fp32 ctx (no-ws path)
// ---------------------------------------------------------------------------
__global__ void k_softmax(const float* __restrict__ e_part, const float* __restrict__ vb,
                          float* __restrict__ a_out) {
    int b = blockIdx.x;
    int t = threadIdx.x;  // 256
    __shared__ float sm[256];
    float ev = 0.f;
    float e  = -1e30f;
    if (t < N_) {
        int m = b * N_ + t;
        ev = e_part[m] + e_part[M_TOT + m] + e_part[2 * M_TOT + m] + e_part[3 * M_TOT + m] + vb[0];
        e = ev;
    }
    sm[t] = e;
    __syncthreads();
    for (int s = 128; s > 0; s >>= 1) {
        if (t < s) sm[t] = fmaxf(sm[t], sm[t + s]);
        __syncthreads();
    }
    float mx = sm[0];
    __syncthreads();
    float ex = (t < N_) ? __expf(ev - mx) : 0.f;
    sm[t] = ex;
    __syncthreads();
    for (int s = 128; s > 0; s >>= 1) {
        if (t < s) sm[t] += sm[t + s];
        __syncthreads();
    }
    float inv = 1.f / sm[0];
    if (t < N_) a_out[(size_t)b * N_ + t] = ex * inv;
}

__global__ void k_ctx_f32(const float* __restrict__ V, const float* __restrict__ a,
                          float* __restrict__ ctx) {
    int b  = blockIdx.x;
    int ch = blockIdx.y;
    int t  = threadIdx.x;  // 128
    __shared__ float as_[N_];
    for (int i = t; i < N_; i += 128) as_[i] = a[(size_t)b * N_ + i];
    __syncthreads();
    int col = ch * 512 + t * 4;
    const f32x4* Vp = reinterpret_cast<const f32x4*>(V + (size_t)b * N_ * VDIM + col);
    f32x4 accv = {0.f, 0.f, 0.f, 0.f};
    for (int n = 0; n < N_; ++n)
        accv += as_[n] * Vp[(size_t)n * (VDIM / 4)];
    *reinterpret_cast<f32x4*>(ctx + (size_t)b * VDIM + col) = accv;
}

// ---------------------------------------------------------------------------
extern "C" void kernel_launch(void* const* d_in, const int* in_sizes, int n_in,
                              void* d_out, int out_size, void* d_ws, size_t ws_size,
                              hipStream_t stream) {
    const float* h  = (const float*)d_in[0];
    const float* V  = (const float*)d_in[1];
    const float* Ww = (const float*)d_in[2];
    const float* Wb = (const float*)d_in[3];
    const float* Uw = (const float*)d_in[4];
    const float* Ub = (const float*)d_in[5];
    const float* vw = (const float*)d_in[6];
    const float* vb = (const float*)d_in[7];

    float* out     = (float*)d_out;
    float* ctx_out = out;                        // B*VDIM floats
    float* a_out   = out + (size_t)B_ * VDIM;    // B*N floats

    const size_t vb_bytes = (size_t)B_ * N_ * VDIM * sizeof(__bf16);  // ~103 MB
    const size_t tail     = 2u * 1024 * 1024 + 256 * 1024 + (size_t)4 * M_TOT * 4 + 4096;
    bool preconv = ws_size >= vb_bytes + tail;

    char*   ws   = (char*)d_ws;
    __bf16* Vb   = (__bf16*)ws;
    char*   rest = ws + (preconv ? vb_bytes : 0);
    __bf16* UwT   = (__bf16*)rest;
    float*  whp   = (float*)(rest + 2u * 1024 * 1024);
    float*  e_prt = (float*)(rest + 2u * 1024 * 1024 + 256 * 1024);

    int grid_cp = preconv ? (384 + NCONVB) : 384;
    k_convprep<<<dim3(grid_cp), 256, 0, stream>>>(
        V, Vb, Uw, UwT, h, Ww, Wb, Ub, whp);
    if (preconv) {
        k_scores128<<<dim3(784), 256, 0, stream>>>(Vb, UwT, whp, vw, e_prt);
        k_ctx_sm<<<dim3(B_, 2), 128, 0, stream>>>(Vb, e_prt, vb, a_out, ctx_out);
    } else {
        k_scores_small<<<dim3(784), 256, 0, stream>>>(V, UwT, whp, vw, e_prt);
        k_softmax<<<dim3(B_), 256, 0, stream>>>(e_prt, vb, a_out);
        k_ctx_f32<<<dim3(B_, 4), 128, 0, stream>>>(V, a_out, ctx_out);
    }
}

// Round 13
// 150.054 us; speedup vs baseline: 1.0682x; 1.0682x over previous
//
#include <hip/hip_runtime.h>
#include <hip/hip_bf16.h>

#define B_    128
#define N_    196
#define HDIM  512
#define VDIM  2048
#define ATT   512
#define M_TOT (B_ * N_)   // 25088

#define BKK 64             // K step (64 bf16 = 128B = 8 chunks of 16B)
#define NT  (VDIM / BKK)   // 32 K-steps
#define BM1 128
#define BN1 128
#define N8     ((B_ * N_ * VDIM) / 8)   // 6,422,528 float8 items
#define NCONVB 6272                      // conv blocks; 4 unrolled items each

typedef float  f32x4  __attribute__((ext_vector_type(4)));
typedef __bf16 bf16x8 __attribute__((ext_vector_type(8)));

__device__ __forceinline__ void gload_lds16(const void* g, void* l) {
    __builtin_amdgcn_global_load_lds(
        (const __attribute__((address_space(1))) void*)g,
        (__attribute__((address_space(3))) void*)l, 16, 0, 0);
}

__device__ __forceinline__ float fast_tanh(float x) {
    float ax = fabsf(x);
    float e  = __expf(-2.f * ax);          // in (0,1], no overflow
    float t  = (1.f - e) / (1.f + e);
    return copysignf(t, x);
}

// ---------------------------------------------------------------------------
// Kernel CP (merged):
//   [0,128):           whp = h@Ww + Wb + Ub   (unroll-8, 16 loads in flight)
//   [128,384):         Uw transpose -> UwT bf16
//   [384,384+NCONVB):  V fp32 -> bf16; 4 items/thread, compile-time stride
//                      (8 loads in flight, 32 VGPRs — TLP via 6272 blocks)
// ---------------------------------------------------------------------------
__global__ void k_convprep(const float* __restrict__ V, __bf16* __restrict__ Vb,
                           const float* __restrict__ Uw, __bf16* __restrict__ UwT,
                           const float* __restrict__ h, const float* __restrict__ Ww,
                           const float* __restrict__ Wb, const float* __restrict__ Ub,
                           float* __restrict__ whp) {
    int t = threadIdx.x;  // 256
    if (blockIdx.x < 128) {
        __shared__ float hs[HDIM];
        int b = blockIdx.x;
        hs[t]       = h[(size_t)b * HDIM + t];
        hs[t + 256] = h[(size_t)b * HDIM + t + 256];
        __syncthreads();
        float a0[8] = {0,0,0,0,0,0,0,0}, a1[8] = {0,0,0,0,0,0,0,0};
        for (int k0 = 0; k0 < HDIM; k0 += 8) {
#pragma unroll
            for (int u = 0; u < 8; ++u) {
                float hv = hs[k0 + u];
                a0[u] += hv * Ww[(size_t)(k0 + u) * ATT + t];
                a1[u] += hv * Ww[(size_t)(k0 + u) * ATT + t + 256];
            }
        }
        float s0 = ((a0[0] + a0[1]) + (a0[2] + a0[3])) + ((a0[4] + a0[5]) + (a0[6] + a0[7]));
        float s1 = ((a1[0] + a1[1]) + (a1[2] + a1[3])) + ((a1[4] + a1[5]) + (a1[6] + a1[7]));
        whp[(size_t)b * ATT + t]       = s0 + Wb[t] + Ub[t];
        whp[(size_t)b * ATT + t + 256] = s1 + Wb[t + 256] + Ub[t + 256];
    } else if (blockIdx.x < 384) {
        __shared__ __bf16 st[64][65];
        int bb = blockIdx.x - 128;
        int k0 = (bb & 31) * 64;
        int c0 = (bb >> 5) * 64;
#pragma unroll
        for (int i = 0; i < 16; ++i) {
            int lin = i * 256 + t;
            int kk = lin >> 6, cc = lin & 63;
            st[kk][cc] = (__bf16)Uw[(size_t)(k0 + kk) * ATT + c0 + cc];
        }
        __syncthreads();
#pragma unroll
        for (int i = 0; i < 16; ++i) {
            int lin = i * 256 + t;
            int cc = lin >> 6, kk = lin & 63;
            UwT[(size_t)(c0 + cc) * VDIM + k0 + kk] = st[kk][cc];
        }
    } else {
        // conv: 4 items/thread, compile-time stride; N8 = 4 * NCONVB * 256
        size_t base = (size_t)(blockIdx.x - 384) * 256 + t;
        const float4* Vp = reinterpret_cast<const float4*>(V);
        float4 xs[4], ys[4];
#pragma unroll
        for (int u = 0; u < 4; ++u) {
            size_t i = base + (size_t)u * ((size_t)NCONVB * 256);
            xs[u] = Vp[2 * i];
            ys[u] = Vp[2 * i + 1];
        }
#pragma unroll
        for (int u = 0; u < 4; ++u) {
            size_t i = base + (size_t)u * ((size_t)NCONVB * 256);
            float4 x = xs[u], y = ys[u];
            bf16x8 w;
            w[0] = (__bf16)x.x; w[1] = (__bf16)x.y; w[2] = (__bf16)x.z; w[3] = (__bf16)x.w;
            w[4] = (__bf16)y.x; w[5] = (__bf16)y.y; w[6] = (__bf16)y.z; w[7] = (__bf16)y.w;
            reinterpret_cast<bf16x8*>(Vb)[i] = w;
        }
    }
}

// ---------------------------------------------------------------------------
// Kernel G (main): 128x128 tile, BK=64, 4 waves, counted-vmcnt depth-2
// pipeline, XOR-swizzled gload_lds both operands. [R7/R10/R11-verified]
// ---------------------------------------------------------------------------
__global__ __launch_bounds__(256, 2) void k_scores128(
    const __bf16* __restrict__ Vb, const __bf16* __restrict__ UwT,
    const float* __restrict__ whp, const float* __restrict__ vw,
    float* __restrict__ e_part)
{
    __shared__ __align__(16) __bf16 As[2][BM1][BKK];   // 32 KB
    __shared__ __align__(16) __bf16 Bs[2][BN1][BKK];   // 32 KB
    __shared__ float red[2][BM1];

    int bid = blockIdx.x;
    int lid = (bid & 7) * (784 / 8) + (bid >> 3);
    int mtile = lid >> 2;         // 0..195
    int cc    = lid & 3;          // 0..3
    int m0 = mtile * BM1;
    int c0 = cc * BN1;
    int t    = threadIdx.x;
    int lane = t & 63;
    int wave = t >> 6;
    int wr = wave >> 1;
    int wc = wave & 1;

    f32x4 acc[4][4];
#pragma unroll
    for (int i = 0; i < 4; ++i)
#pragma unroll
        for (int j = 0; j < 4; ++j) acc[i][j] = (f32x4){0.f, 0.f, 0.f, 0.f};

    int lr  = lane >> 3;
    int csw = ((lane & 7) ^ lr) * 8;
    const __bf16* AgS = Vb  + (size_t)(m0 + wave * 32 + lr) * VDIM + csw;
    const __bf16* BgS = UwT + (size_t)(c0 + wave * 32 + lr) * VDIM + csw;
    __bf16* Al0 = &As[0][wave * 32 + lr][(lane & 7) * 8];
    __bf16* Bl0 = &Bs[0][wave * 32 + lr][(lane & 7) * 8];

#define STAGE(buf, kt)                                                          \
    do {                                                                        \
        _Pragma("unroll")                                                       \
        for (int i = 0; i < 4; ++i) {                                           \
            gload_lds16(AgS + (kt) * BKK + (size_t)i * 8 * VDIM,                \
                        Al0 + (buf) * (BM1 * BKK) + i * 8 * BKK);               \
            gload_lds16(BgS + (kt) * BKK + (size_t)i * 8 * VDIM,                \
                        Bl0 + (buf) * (BN1 * BKK) + i * 8 * BKK);               \
        }                                                                       \
    } while (0)

    int lcol = lane & 15;
    int lg4  = lane >> 4;
    int arow0 = wr * 64;
    int bcol0 = wc * 64;

    STAGE(0, 0);
    __builtin_amdgcn_sched_barrier(0);   // pin issue order: tile0 before tile1
    STAGE(1, 1);

    for (int kt = 0; kt < NT; ++kt) {
        int buf = kt & 1;
        if (kt < NT - 1) {
            asm volatile("s_waitcnt vmcnt(8)\n\ts_barrier" ::: "memory");
        } else {
            asm volatile("s_waitcnt vmcnt(0)\n\ts_barrier" ::: "memory");
        }
        __builtin_amdgcn_sched_barrier(0);

#pragma unroll
        for (int ks = 0; ks < 2; ++ks) {
            bf16x8 af[4], bfr[4];
#pragma unroll
            for (int i = 0; i < 4; ++i) {
                int row = arow0 + i * 16 + lcol;
                int ch  = ((ks * 4 + lg4) ^ (row & 7)) * 8;
                af[i] = *reinterpret_cast<const bf16x8*>(&As[buf][row][ch]);
            }
#pragma unroll
            for (int j = 0; j < 4; ++j) {
                int row = bcol0 + j * 16 + lcol;
                int ch  = ((ks * 4 + lg4) ^ (row & 7)) * 8;
                bfr[j] = *reinterpret_cast<const bf16x8*>(&Bs[buf][row][ch]);
            }
            __builtin_amdgcn_s_setprio(1);
#pragma unroll
            for (int i = 0; i < 4; ++i)
#pragma unroll
                for (int j = 0; j < 4; ++j)
                    acc[i][j] = __builtin_amdgcn_mfma_f32_16x16x32_bf16(af[i], bfr[j], acc[i][j], 0, 0, 0);
            __builtin_amdgcn_s_setprio(0);
        }

        __builtin_amdgcn_sched_barrier(0);
        asm volatile("s_barrier" ::: "memory");   // buf free: all waves consumed it
        if (kt + 2 < NT) STAGE(buf, kt + 2);
    }
#undef STAGE

    // ---- epilogue: rowsum over this block's 128 cols ----
    int lrow4 = lg4 * 4;
#pragma unroll
    for (int i = 0; i < 4; ++i) {
        float rs[4] = {0.f, 0.f, 0.f, 0.f};
#pragma unroll
        for (int j = 0; j < 4; ++j) {
            int col = c0 + wc * 64 + j * 16 + lcol;
            float vwv = vw[col];
#pragma unroll
            for (int r = 0; r < 4; ++r) {
                int m = m0 + wr * 64 + i * 16 + lrow4 + r;
                int b = m / N_;
                float x = acc[i][j][r] + whp[(size_t)b * ATT + col];
                rs[r] += fast_tanh(x) * vwv;
            }
        }
#pragma unroll
        for (int r = 0; r < 4; ++r) {
            float v = rs[r];
            v += __shfl_xor(v, 1);
            v += __shfl_xor(v, 2);
            v += __shfl_xor(v, 4);
            v += __shfl_xor(v, 8);
            if (lcol == 0)
                red[wc][wr * 64 + i * 16 + lrow4 + r] = v;
        }
    }
    __syncthreads();
    if (t < BM1)
        e_part[(size_t)cc * M_TOT + m0 + t] = red[0][t] + red[1][t];
}

// ---------------------------------------------------------------------------
// Kernel G (fallback, no-ws path): 128x128, fp32 A reg-staged (R3-proven).
// ---------------------------------------------------------------------------
__global__ __launch_bounds__(256, 2) void k_scores_small(
    const float* __restrict__ Vf, const __bf16* __restrict__ UwT,
    const float* __restrict__ whp, const float* __restrict__ vw,
    float* __restrict__ e_part)
{
    __shared__ __align__(16) __bf16 As[2][BM1][BKK];
    __shared__ __align__(16) __bf16 Bs[2][BN1][BKK];
    __shared__ float red[2][BM1];

    int bid = blockIdx.x;
    int lid = (bid & 7) * (784 / 8) + (bid >> 3);
    int mtile = lid >> 2;
    int cc    = lid & 3;
    int m0 = mtile * BM1;
    int c0 = cc * BN1;
    int t    = threadIdx.x;
    int lane = t & 63;
    int wave = t >> 6;
    int wr = wave >> 1;
    int wc = wave & 1;

    f32x4 acc[4][4];
#pragma unroll
    for (int i = 0; i < 4; ++i)
#pragma unroll
        for (int j = 0; j < 4; ++j) acc[i][j] = (f32x4){0.f, 0.f, 0.f, 0.f};

    int lr  = lane >> 3;
    int csw = ((lane & 7) ^ lr) * 8;
    const __bf16* BgS = UwT + (size_t)(c0 + wave * 32 + lr) * VDIM + csw;
    __bf16* Bl0 = &Bs[0][wave * 32 + lr][(lane & 7) * 8];

    int ra = t >> 1;
    int ka = (t & 1) * 32;
    const float* Af = Vf + (size_t)(m0 + ra) * VDIM + ka;

#define STAGE1(buf, kt)                                                         \
    do {                                                                        \
        _Pragma("unroll")                                                       \
        for (int i = 0; i < 4; ++i)                                             \
            gload_lds16(BgS + (kt) * BKK + (size_t)i * 8 * VDIM,                \
                        Bl0 + (buf) * (BN1 * BKK) + i * 8 * BKK);               \
        const float4* src = reinterpret_cast<const float4*>(Af + (kt) * BKK);   \
        _Pragma("unroll")                                                       \
        for (int i = 0; i < 4; ++i) {                                           \
            float4 x = src[2 * i];                                              \
            float4 y = src[2 * i + 1];                                          \
            bf16x8 w;                                                           \
            w[0] = (__bf16)x.x; w[1] = (__bf16)x.y;                             \
            w[2] = (__bf16)x.z; w[3] = (__bf16)x.w;                             \
            w[4] = (__bf16)y.x; w[5] = (__bf16)y.y;                             \
            w[6] = (__bf16)y.z; w[7] = (__bf16)y.w;                             \
            int ch = (((t & 1) * 4 + i) ^ (ra & 7)) * 8;                        \
            *reinterpret_cast<bf16x8*>(&As[buf][ra][ch]) = w;                   \
        }                                                                       \
    } while (0)

    int lcol = lane & 15;
    int lg4  = lane >> 4;
    int arow0 = wr * 64;
    int bcol0 = wc * 64;

    STAGE1(0, 0);
    __syncthreads();

    for (int kt = 0; kt < NT; ++kt) {
        int buf = kt & 1;
        if (kt + 1 < NT) STAGE1(buf ^ 1, kt + 1);
#pragma unroll
        for (int ks = 0; ks < 2; ++ks) {
            bf16x8 af[4], bfr[4];
#pragma unroll
            for (int i = 0; i < 4; ++i) {
                int row = arow0 + i * 16 + lcol;
                int ch  = ((ks * 4 + lg4) ^ (row & 7)) * 8;
                af[i] = *reinterpret_cast<const bf16x8*>(&As[buf][row][ch]);
            }
#pragma unroll
            for (int j = 0; j < 4; ++j) {
                int row = bcol0 + j * 16 + lcol;
                int ch  = ((ks * 4 + lg4) ^ (row & 7)) * 8;
                bfr[j] = *reinterpret_cast<const bf16x8*>(&Bs[buf][row][ch]);
            }
#pragma unroll
            for (int i = 0; i < 4; ++i)
#pragma unroll
                for (int j = 0; j < 4; ++j)
                    acc[i][j] = __builtin_amdgcn_mfma_f32_16x16x32_bf16(af[i], bfr[j], acc[i][j], 0, 0, 0);
        }
        __syncthreads();
    }
#undef STAGE1

    int lrow4 = lg4 * 4;
#pragma unroll
    for (int i = 0; i < 4; ++i) {
        float rs[4] = {0.f, 0.f, 0.f, 0.f};
#pragma unroll
        for (int j = 0; j < 4; ++j) {
            int col = c0 + wc * 64 + j * 16 + lcol;
            float vwv = vw[col];
#pragma unroll
            for (int r = 0; r < 4; ++r) {
                int m = m0 + wr * 64 + i * 16 + lrow4 + r;
                int b = m / N_;
                float x = acc[i][j][r] + whp[(size_t)b * ATT + col];
                rs[r] += fast_tanh(x) * vwv;
            }
        }
#pragma unroll
        for (int r = 0; r < 4; ++r) {
            float v = rs[r];
            v += __shfl_xor(v, 1);
            v += __shfl_xor(v, 2);
            v += __shfl_xor(v, 4);
            v += __shfl_xor(v, 8);
            if (lcol == 0)
                red[wc][wr * 64 + i * 16 + lrow4 + r] = v;
        }
    }
    __syncthreads();
    if (t < BM1)
        e_part[(size_t)cc * M_TOT + m0 + t] = red[0][t] + red[1][t];
}

// ---------------------------------------------------------------------------
// Kernel CS (fused softmax + ctx, bf16 V): each (b,ch) block recomputes the
// softmax over N=196 from the 4 e-partials (identical fp ops -> identical a
// in both ch blocks, deterministic); ch==0 writes a_out; both accumulate ctx.
// ---------------------------------------------------------------------------
__global__ void k_ctx_sm(const __bf16* __restrict__ Vb, const float* __restrict__ e_part,
                         const float* __restrict__ vb, float* __restrict__ a_out,
                         float* __restrict__ ctx) {
    int b  = blockIdx.x;   // 128
    int ch = blockIdx.y;   // 2 chunks of 1024 cols
    int t  = threadIdx.x;  // 128
    __shared__ float sm[128];
    __shared__ float as_[N_];

    int n0 = t, n1 = t + 128;
    float ev0 = 0.f, ev1 = 0.f, e0 = -1e30f, e1 = -1e30f;
    {
        int m = b * N_ + n0;
        ev0 = e_part[m] + e_part[M_TOT + m] + e_part[2 * M_TOT + m] + e_part[3 * M_TOT + m] + vb[0];
        e0 = ev0;
    }
    if (n1 < N_) {
        int m = b * N_ + n1;
        ev1 = e_part[m] + e_part[M_TOT + m] + e_part[2 * M_TOT + m] + e_part[3 * M_TOT + m] + vb[0];
        e1 = ev1;
    }
    sm[t] = fmaxf(e0, e1);
    __syncthreads();
    for (int s = 64; s > 0; s >>= 1) {
        if (t < s) sm[t] = fmaxf(sm[t], sm[t + s]);
        __syncthreads();
    }
    float mx = sm[0];
    __syncthreads();
    float x0 = __expf(ev0 - mx);
    float x1 = (n1 < N_) ? __expf(ev1 - mx) : 0.f;
    sm[t] = x0 + x1;
    __syncthreads();
    for (int s = 64; s > 0; s >>= 1) {
        if (t < s) sm[t] += sm[t + s];
        __syncthreads();
    }
    float inv = 1.f / sm[0];
    as_[n0] = x0 * inv;
    if (n1 < N_) as_[n1] = x1 * inv;
    if (ch == 0) {
        a_out[(size_t)b * N_ + n0] = x0 * inv;
        if (n1 < N_) a_out[(size_t)b * N_ + n1] = x1 * inv;
    }
    __syncthreads();

    int col = ch * 1024 + t * 8;
    const __bf16* Vp = Vb + (size_t)b * N_ * VDIM + col;
    float av[8] = {0.f, 0.f, 0.f, 0.f, 0.f, 0.f, 0.f, 0.f};
    for (int n = 0; n < N_; ++n) {
        bf16x8 v = *reinterpret_cast<const bf16x8*>(Vp + (size_t)n * VDIM);
        float an = as_[n];
#pragma unroll
        for (int j = 0; j < 8; ++j) av[j] += an * (float)v[j];
    }
    f32x4 lo = {av[0], av[1], av[2], av[3]};
    f32x4 hi = {av[4], av[5], av[6], av[7]};
    f32x4* dst = reinterpret_cast<f32x4*>(ctx + (size_t)b * VDIM + col);
    dst[0] = lo;
    dst[1] = hi;
}

// ---------------------------------------------------------------------------
// Fallback softmax + fp32 ctx (no-ws path)
// ---------------------------------------------------------------------------
__global__ void k_softmax(const float* __restrict__ e_part, const float* __restrict__ vb,
                          float* __restrict__ a_out) {
    int b = blockIdx.x;
    int t = threadIdx.x;  // 256
    __shared__ float sm[256];
    float ev = 0.f;
    float e  = -1e30f;
    if (t < N_) {
        int m = b * N_ + t;
        ev = e_part[m] + e_part[M_TOT + m] + e_part[2 * M_TOT + m] + e_part[3 * M_TOT + m] + vb[0];
        e = ev;
    }
    sm[t] = e;
    __syncthreads();
    for (int s = 128; s > 0; s >>= 1) {
        if (t < s) sm[t] = fmaxf(sm[t], sm[t + s]);
        __syncthreads();
    }
    float mx = sm[0];
    __syncthreads();
    float ex = (t < N_) ? __expf(ev - mx) : 0.f;
    sm[t] = ex;
    __syncthreads();
    for (int s = 128; s > 0; s >>= 1) {
        if (t < s) sm[t] += sm[t + s];
        __syncthreads();
    }
    float inv = 1.f / sm[0];
    if (t < N_) a_out[(size_t)b * N_ + t] = ex * inv;
}

__global__ void k_ctx_f32(const float* __restrict__ V, const float* __restrict__ a,
                          float* __restrict__ ctx) {
    int b  = blockIdx.x;
    int ch = blockIdx.y;
    int t  = threadIdx.x;  // 128
    __shared__ float as_[N_];
    for (int i = t; i < N_; i += 128) as_[i] = a[(size_t)b * N_ + i];
    __syncthreads();
    int col = ch * 512 + t * 4;
    const f32x4* Vp = reinterpret_cast<const f32x4*>(V + (size_t)b * N_ * VDIM + col);
    f32x4 accv = {0.f, 0.f, 0.f, 0.f};
    for (int n = 0; n < N_; ++n)
        accv += as_[n] * Vp[(size_t)n * (VDIM / 4)];
    *reinterpret_cast<f32x4*>(ctx + (size_t)b * VDIM + col) = accv;
}

// ---------------------------------------------------------------------------
extern "C" void kernel_launch(void* const* d_in, const int* in_sizes, int n_in,
                              void* d_out, int out_size, void* d_ws, size_t ws_size,
                              hipStream_t stream) {
    const float* h  = (const float*)d_in[0];
    const float* V  = (const float*)d_in[1];
    const float* Ww = (const float*)d_in[2];
    const float* Wb = (const float*)d_in[3];
    const float* Uw = (const float*)d_in[4];
    const float* Ub = (const float*)d_in[5];
    const float* vw = (const float*)d_in[6];
    const float* vb = (const float*)d_in[7];

    float* out     = (float*)d_out;
    float* ctx_out = out;                        // B*VDIM floats
    float* a_out   = out + (size_t)B_ * VDIM;    // B*N floats

    const size_t vb_bytes = (size_t)B_ * N_ * VDIM * sizeof(__bf16);  // ~103 MB
    const size_t tail     = 2u * 1024 * 1024 + 256 * 1024 + (size_t)4 * M_TOT * 4 + 4096;
    bool preconv = ws_size >= vb_bytes + tail;

    char*   ws   = (char*)d_ws;
    __bf16* Vb   = (__bf16*)ws;
    char*   rest = ws + (preconv ? vb_bytes : 0);
    __bf16* UwT   = (__bf16*)rest;
    float*  whp   = (float*)(rest + 2u * 1024 * 1024);
    float*  e_prt = (float*)(rest + 2u * 1024 * 1024 + 256 * 1024);

    int grid_cp = preconv ? (384 + NCONVB) : 384;
    k_convprep<<<dim3(grid_cp), 256, 0, stream>>>(
        V, Vb, Uw, UwT, h, Ww, Wb, Ub, whp);
    if (preconv) {
        k_scores128<<<dim3(784), 256, 0, stream>>>(Vb, UwT, whp, vw, e_prt);
        k_ctx_sm<<<dim3(B_, 2), 128, 0, stream>>>(Vb, e_prt, vb, a_out, ctx_out);
    } else {
        k_scores_small<<<dim3(784), 256, 0, stream>>>(V, UwT, whp, vw, e_prt);
        k_softmax<<<dim3(B_), 256, 0, stream>>>(e_prt, vb, a_out);
        k_ctx_f32<<<dim3(B_, 4), 128, 0, stream>>>(V, a_out, ctx_out);
    }
}

// Round 14
// 149.361 us; speedup vs baseline: 1.0732x; 1.0046x over previous
//
#include <hip/hip_runtime.h>
#include <hip/hip_bf16.h>

#define B_    128
#define N_    196
#define HDIM  512
#define VDIM  2048
#define ATT   512
#define M_TOT (B_ * N_)   // 25088

#define BKK 64             // K step (64 bf16 = 128B = 8 chunks of 16B)
#define NT  (VDIM / BKK)   // 32 K-steps
#define BM1 128
#define BN1 128
#define N8     ((B_ * N_ * VDIM) / 8)   // 6,422,528 float8 items
#define NCONVB 12544                     // conv blocks; 2 items each (TLP)

typedef float  f32x4  __attribute__((ext_vector_type(4)));
typedef __bf16 bf16x8 __attribute__((ext_vector_type(8)));
typedef __bf16 bf16x4 __attribute__((ext_vector_type(4)));

__device__ __forceinline__ void gload_lds16(const void* g, void* l) {
    __builtin_amdgcn_global_load_lds(
        (const __attribute__((address_space(1))) void*)g,
        (__attribute__((address_space(3))) void*)l, 16, 0, 0);
}

__device__ __forceinline__ float fast_tanh(float x) {
    float ax = fabsf(x);
    float e  = __expf(-2.f * ax);          // in (0,1], no overflow
    float t  = (1.f - e) / (1.f + e);
    return copysignf(t, x);
}

// ---------------------------------------------------------------------------
// Kernel CP (merged):
//   [0,128):           whp = h@Ww + Wb + Ub   (unroll-8, 16 loads in flight)
//   [128,384):         Uw transpose -> UwT bf16
//   [384,384+NCONVB):  V fp32 -> bf16; 2 items/thread (4 loads in flight),
//                      TLP via 12544 blocks (~49 waves/CU)
// ---------------------------------------------------------------------------
__global__ void k_convprep(const float* __restrict__ V, __bf16* __restrict__ Vb,
                           const float* __restrict__ Uw, __bf16* __restrict__ UwT,
                           const float* __restrict__ h, const float* __restrict__ Ww,
                           const float* __restrict__ Wb, const float* __restrict__ Ub,
                           float* __restrict__ whp) {
    int t = threadIdx.x;  // 256
    if (blockIdx.x < 128) {
        __shared__ float hs[HDIM];
        int b = blockIdx.x;
        hs[t]       = h[(size_t)b * HDIM + t];
        hs[t + 256] = h[(size_t)b * HDIM + t + 256];
        __syncthreads();
        float a0[8] = {0,0,0,0,0,0,0,0}, a1[8] = {0,0,0,0,0,0,0,0};
        for (int k0 = 0; k0 < HDIM; k0 += 8) {
#pragma unroll
            for (int u = 0; u < 8; ++u) {
                float hv = hs[k0 + u];
                a0[u] += hv * Ww[(size_t)(k0 + u) * ATT + t];
                a1[u] += hv * Ww[(size_t)(k0 + u) * ATT + t + 256];
            }
        }
        float s0 = ((a0[0] + a0[1]) + (a0[2] + a0[3])) + ((a0[4] + a0[5]) + (a0[6] + a0[7]));
        float s1 = ((a1[0] + a1[1]) + (a1[2] + a1[3])) + ((a1[4] + a1[5]) + (a1[6] + a1[7]));
        whp[(size_t)b * ATT + t]       = s0 + Wb[t] + Ub[t];
        whp[(size_t)b * ATT + t + 256] = s1 + Wb[t + 256] + Ub[t + 256];
    } else if (blockIdx.x < 384) {
        __shared__ __bf16 st[64][65];
        int bb = blockIdx.x - 128;
        int k0 = (bb & 31) * 64;
        int c0 = (bb >> 5) * 64;
#pragma unroll
        for (int i = 0; i < 16; ++i) {
            int lin = i * 256 + t;
            int kk = lin >> 6, cc = lin & 63;
            st[kk][cc] = (__bf16)Uw[(size_t)(k0 + kk) * ATT + c0 + cc];
        }
        __syncthreads();
#pragma unroll
        for (int i = 0; i < 16; ++i) {
            int lin = i * 256 + t;
            int cc = lin >> 6, kk = lin & 63;
            UwT[(size_t)(c0 + cc) * VDIM + k0 + kk] = st[kk][cc];
        }
    } else {
        // conv: 2 items/thread, compile-time stride; N8 = 2 * NCONVB * 256
        size_t base = (size_t)(blockIdx.x - 384) * 256 + t;
        const float4* Vp = reinterpret_cast<const float4*>(V);
        float4 xs[2], ys[2];
#pragma unroll
        for (int u = 0; u < 2; ++u) {
            size_t i = base + (size_t)u * ((size_t)NCONVB * 256);
            xs[u] = Vp[2 * i];
            ys[u] = Vp[2 * i + 1];
        }
#pragma unroll
        for (int u = 0; u < 2; ++u) {
            size_t i = base + (size_t)u * ((size_t)NCONVB * 256);
            float4 x = xs[u], y = ys[u];
            bf16x8 w;
            w[0] = (__bf16)x.x; w[1] = (__bf16)x.y; w[2] = (__bf16)x.z; w[3] = (__bf16)x.w;
            w[4] = (__bf16)y.x; w[5] = (__bf16)y.y; w[6] = (__bf16)y.z; w[7] = (__bf16)y.w;
            reinterpret_cast<bf16x8*>(Vb)[i] = w;
        }
    }
}

// ---------------------------------------------------------------------------
// Kernel G (main): 128x128 tile, BK=64, 4 waves, counted-vmcnt depth-2
// pipeline, XOR-swizzled gload_lds both operands. [R7/R10/R11/R13-verified]
// ---------------------------------------------------------------------------
__global__ __launch_bounds__(256, 2) void k_scores128(
    const __bf16* __restrict__ Vb, const __bf16* __restrict__ UwT,
    const float* __restrict__ whp, const float* __restrict__ vw,
    float* __restrict__ e_part)
{
    __shared__ __align__(16) __bf16 As[2][BM1][BKK];   // 32 KB
    __shared__ __align__(16) __bf16 Bs[2][BN1][BKK];   // 32 KB
    __shared__ float red[2][BM1];

    int bid = blockIdx.x;
    int lid = (bid & 7) * (784 / 8) + (bid >> 3);
    int mtile = lid >> 2;         // 0..195
    int cc    = lid & 3;          // 0..3
    int m0 = mtile * BM1;
    int c0 = cc * BN1;
    int t    = threadIdx.x;
    int lane = t & 63;
    int wave = t >> 6;
    int wr = wave >> 1;
    int wc = wave & 1;

    f32x4 acc[4][4];
#pragma unroll
    for (int i = 0; i < 4; ++i)
#pragma unroll
        for (int j = 0; j < 4; ++j) acc[i][j] = (f32x4){0.f, 0.f, 0.f, 0.f};

    int lr  = lane >> 3;
    int csw = ((lane & 7) ^ lr) * 8;
    const __bf16* AgS = Vb  + (size_t)(m0 + wave * 32 + lr) * VDIM + csw;
    const __bf16* BgS = UwT + (size_t)(c0 + wave * 32 + lr) * VDIM + csw;
    __bf16* Al0 = &As[0][wave * 32 + lr][(lane & 7) * 8];
    __bf16* Bl0 = &Bs[0][wave * 32 + lr][(lane & 7) * 8];

#define STAGE(buf, kt)                                                          \
    do {                                                                        \
        _Pragma("unroll")                                                       \
        for (int i = 0; i < 4; ++i) {                                           \
            gload_lds16(AgS + (kt) * BKK + (size_t)i * 8 * VDIM,                \
                        Al0 + (buf) * (BM1 * BKK) + i * 8 * BKK);               \
            gload_lds16(BgS + (kt) * BKK + (size_t)i * 8 * VDIM,                \
                        Bl0 + (buf) * (BN1 * BKK) + i * 8 * BKK);               \
        }                                                                       \
    } while (0)

    int lcol = lane & 15;
    int lg4  = lane >> 4;
    int arow0 = wr * 64;
    int bcol0 = wc * 64;

    STAGE(0, 0);
    __builtin_amdgcn_sched_barrier(0);   // pin issue order: tile0 before tile1
    STAGE(1, 1);

    for (int kt = 0; kt < NT; ++kt) {
        int buf = kt & 1;
        if (kt < NT - 1) {
            asm volatile("s_waitcnt vmcnt(8)\n\ts_barrier" ::: "memory");
        } else {
            asm volatile("s_waitcnt vmcnt(0)\n\ts_barrier" ::: "memory");
        }
        __builtin_amdgcn_sched_barrier(0);

#pragma unroll
        for (int ks = 0; ks < 2; ++ks) {
            bf16x8 af[4], bfr[4];
#pragma unroll
            for (int i = 0; i < 4; ++i) {
                int row = arow0 + i * 16 + lcol;
                int ch  = ((ks * 4 + lg4) ^ (row & 7)) * 8;
                af[i] = *reinterpret_cast<const bf16x8*>(&As[buf][row][ch]);
            }
#pragma unroll
            for (int j = 0; j < 4; ++j) {
                int row = bcol0 + j * 16 + lcol;
                int ch  = ((ks * 4 + lg4) ^ (row & 7)) * 8;
                bfr[j] = *reinterpret_cast<const bf16x8*>(&Bs[buf][row][ch]);
            }
            __builtin_amdgcn_s_setprio(1);
#pragma unroll
            for (int i = 0; i < 4; ++i)
#pragma unroll
                for (int j = 0; j < 4; ++j)
                    acc[i][j] = __builtin_amdgcn_mfma_f32_16x16x32_bf16(af[i], bfr[j], acc[i][j], 0, 0, 0);
            __builtin_amdgcn_s_setprio(0);
        }

        __builtin_amdgcn_sched_barrier(0);
        asm volatile("s_barrier" ::: "memory");   // buf free: all waves consumed it
        if (kt + 2 < NT) STAGE(buf, kt + 2);
    }
#undef STAGE

    // ---- epilogue: rowsum over this block's 128 cols ----
    int lrow4 = lg4 * 4;
#pragma unroll
    for (int i = 0; i < 4; ++i) {
        float rs[4] = {0.f, 0.f, 0.f, 0.f};
#pragma unroll
        for (int j = 0; j < 4; ++j) {
            int col = c0 + wc * 64 + j * 16 + lcol;
            float vwv = vw[col];
#pragma unroll
            for (int r = 0; r < 4; ++r) {
                int m = m0 + wr * 64 + i * 16 + lrow4 + r;
                int b = m / N_;
                float x = acc[i][j][r] + whp[(size_t)b * ATT + col];
                rs[r] += fast_tanh(x) * vwv;
            }
        }
#pragma unroll
        for (int r = 0; r < 4; ++r) {
            float v = rs[r];
            v += __shfl_xor(v, 1);
            v += __shfl_xor(v, 2);
            v += __shfl_xor(v, 4);
            v += __shfl_xor(v, 8);
            if (lcol == 0)
                red[wc][wr * 64 + i * 16 + lrow4 + r] = v;
        }
    }
    __syncthreads();
    if (t < BM1)
        e_part[(size_t)cc * M_TOT + m0 + t] = red[0][t] + red[1][t];
}

// ---------------------------------------------------------------------------
// Kernel G (fallback, no-ws path): 128x128, fp32 A reg-staged (R3-proven).
// ---------------------------------------------------------------------------
__global__ __launch_bounds__(256, 2) void k_scores_small(
    const float* __restrict__ Vf, const __bf16* __restrict__ UwT,
    const float* __restrict__ whp, const float* __restrict__ vw,
    float* __restrict__ e_part)
{
    __shared__ __align__(16) __bf16 As[2][BM1][BKK];
    __shared__ __align__(16) __bf16 Bs[2][BN1][BKK];
    __shared__ float red[2][BM1];

    int bid = blockIdx.x;
    int lid = (bid & 7) * (784 / 8) + (bid >> 3);
    int mtile = lid >> 2;
    int cc    = lid & 3;
    int m0 = mtile * BM1;
    int c0 = cc * BN1;
    int t    = threadIdx.x;
    int lane = t & 63;
    int wave = t >> 6;
    int wr = wave >> 1;
    int wc = wave & 1;

    f32x4 acc[4][4];
#pragma unroll
    for (int i = 0; i < 4; ++i)
#pragma unroll
        for (int j = 0; j < 4; ++j) acc[i][j] = (f32x4){0.f, 0.f, 0.f, 0.f};

    int lr  = lane >> 3;
    int csw = ((lane & 7) ^ lr) * 8;
    const __bf16* BgS = UwT + (size_t)(c0 + wave * 32 + lr) * VDIM + csw;
    __bf16* Bl0 = &Bs[0][wave * 32 + lr][(lane & 7) * 8];

    int ra = t >> 1;
    int ka = (t & 1) * 32;
    const float* Af = Vf + (size_t)(m0 + ra) * VDIM + ka;

#define STAGE1(buf, kt)                                                         \
    do {                                                                        \
        _Pragma("unroll")                                                       \
        for (int i = 0; i < 4; ++i)                                             \
            gload_lds16(BgS + (kt) * BKK + (size_t)i * 8 * VDIM,                \
                        Bl0 + (buf) * (BN1 * BKK) + i * 8 * BKK);               \
        const float4* src = reinterpret_cast<const float4*>(Af + (kt) * BKK);   \
        _Pragma("unroll")                                                       \
        for (int i = 0; i < 4; ++i) {                                           \
            float4 x = src[2 * i];                                              \
            float4 y = src[2 * i + 1];                                          \
            bf16x8 w;                                                           \
            w[0] = (__bf16)x.x; w[1] = (__bf16)x.y;                             \
            w[2] = (__bf16)x.z; w[3] = (__bf16)x.w;                             \
            w[4] = (__bf16)y.x; w[5] = (__bf16)y.y;                             \
            w[6] = (__bf16)y.z; w[7] = (__bf16)y.w;                             \
            int ch = (((t & 1) * 4 + i) ^ (ra & 7)) * 8;                        \
            *reinterpret_cast<bf16x8*>(&As[buf][ra][ch]) = w;                   \
        }                                                                       \
    } while (0)

    int lcol = lane & 15;
    int lg4  = lane >> 4;
    int arow0 = wr * 64;
    int bcol0 = wc * 64;

    STAGE1(0, 0);
    __syncthreads();

    for (int kt = 0; kt < NT; ++kt) {
        int buf = kt & 1;
        if (kt + 1 < NT) STAGE1(buf ^ 1, kt + 1);
#pragma unroll
        for (int ks = 0; ks < 2; ++ks) {
            bf16x8 af[4], bfr[4];
#pragma unroll
            for (int i = 0; i < 4; ++i) {
                int row = arow0 + i * 16 + lcol;
                int ch  = ((ks * 4 + lg4) ^ (row & 7)) * 8;
                af[i] = *reinterpret_cast<const bf16x8*>(&As[buf][row][ch]);
            }
#pragma unroll
            for (int j = 0; j < 4; ++j) {
                int row = bcol0 + j * 16 + lcol;
                int ch  = ((ks * 4 + lg4) ^ (row & 7)) * 8;
                bfr[j] = *reinterpret_cast<const bf16x8*>(&Bs[buf][row][ch]);
            }
#pragma unroll
            for (int i = 0; i < 4; ++i)
#pragma unroll
                for (int j = 0; j < 4; ++j)
                    acc[i][j] = __builtin_amdgcn_mfma_f32_16x16x32_bf16(af[i], bfr[j], acc[i][j], 0, 0, 0);
        }
        __syncthreads();
    }
#undef STAGE1

    int lrow4 = lg4 * 4;
#pragma unroll
    for (int i = 0; i < 4; ++i) {
        float rs[4] = {0.f, 0.f, 0.f, 0.f};
#pragma unroll
        for (int j = 0; j < 4; ++j) {
            int col = c0 + wc * 64 + j * 16 + lcol;
            float vwv = vw[col];
#pragma unroll
            for (int r = 0; r < 4; ++r) {
                int m = m0 + wr * 64 + i * 16 + lrow4 + r;
                int b = m / N_;
                float x = acc[i][j][r] + whp[(size_t)b * ATT + col];
                rs[r] += fast_tanh(x) * vwv;
            }
        }
#pragma unroll
        for (int r = 0; r < 4; ++r) {
            float v = rs[r];
            v += __shfl_xor(v, 1);
            v += __shfl_xor(v, 2);
            v += __shfl_xor(v, 4);
            v += __shfl_xor(v, 8);
            if (lcol == 0)
                red[wc][wr * 64 + i * 16 + lrow4 + r] = v;
        }
    }
    __syncthreads();
    if (t < BM1)
        e_part[(size_t)cc * M_TOT + m0 + t] = red[0][t] + red[1][t];
}

// ---------------------------------------------------------------------------
// Kernel CS (fused softmax + ctx, bf16 V): 256 threads (4 waves/block).
// Each (b,ch) block recomputes softmax over N=196 from the 4 e-partials
// (identical fp ops in both ch blocks -> deterministic); ch==0 writes a_out;
// both accumulate 1024 ctx cols (4 cols/thread, 8B coalesced loads).
// ---------------------------------------------------------------------------
__global__ void k_ctx_sm(const __bf16* __restrict__ Vb, const float* __restrict__ e_part,
                         const float* __restrict__ vb, float* __restrict__ a_out,
                         float* __restrict__ ctx) {
    int b  = blockIdx.x;   // 128
    int ch = blockIdx.y;   // 2 chunks of 1024 cols
    int t  = threadIdx.x;  // 256
    __shared__ float sm[256];
    __shared__ float as_[N_];

    float ev = 0.f;
    float e  = -1e30f;
    if (t < N_) {
        int m = b * N_ + t;
        ev = e_part[m] + e_part[M_TOT + m] + e_part[2 * M_TOT + m] + e_part[3 * M_TOT + m] + vb[0];
        e = ev;
    }
    sm[t] = e;
    __syncthreads();
    for (int s = 128; s > 0; s >>= 1) {
        if (t < s) sm[t] = fmaxf(sm[t], sm[t + s]);
        __syncthreads();
    }
    float mx = sm[0];
    __syncthreads();
    float ex = (t < N_) ? __expf(ev - mx) : 0.f;
    sm[t] = ex;
    __syncthreads();
    for (int s = 128; s > 0; s >>= 1) {
        if (t < s) sm[t] += sm[t + s];
        __syncthreads();
    }
    float inv = 1.f / sm[0];
    if (t < N_) {
        as_[t] = ex * inv;
        if (ch == 0) a_out[(size_t)b * N_ + t] = ex * inv;
    }
    __syncthreads();

    // ctx: 4 cols/thread over this chunk of 1024 (8B bf16x4 loads)
    int col = ch * 1024 + t * 4;
    const __bf16* Vp = Vb + (size_t)b * N_ * VDIM + col;
    float av[4] = {0.f, 0.f, 0.f, 0.f};
    for (int n = 0; n < N_; ++n) {
        bf16x4 v = *reinterpret_cast<const bf16x4*>(Vp + (size_t)n * VDIM);
        float an = as_[n];
#pragma unroll
        for (int j = 0; j < 4; ++j) av[j] += an * (float)v[j];
    }
    f32x4 o = {av[0], av[1], av[2], av[3]};
    *reinterpret_cast<f32x4*>(ctx + (size_t)b * VDIM + col) = o;
}

// ---------------------------------------------------------------------------
// Fallback softmax + fp32 ctx (no-ws path)
// ---------------------------------------------------------------------------
__global__ void k_softmax(const float* __restrict__ e_part, const float* __restrict__ vb,
                          float* __restrict__ a_out) {
    int b = blockIdx.x;
    int t = threadIdx.x;  // 256
    __shared__ float sm[256];
    float ev = 0.f;
    float e  = -1e30f;
    if (t < N_) {
        int m = b * N_ + t;
        ev = e_part[m] + e_part[M_TOT + m] + e_part[2 * M_TOT + m] + e_part[3 * M_TOT + m] + vb[0];
        e = ev;
    }
    sm[t] = e;
    __syncthreads();
    for (int s = 128; s > 0; s >>= 1) {
        if (t < s) sm[t] = fmaxf(sm[t], sm[t + s]);
        __syncthreads();
    }
    float mx = sm[0];
    __syncthreads();
    float ex = (t < N_) ? __expf(ev - mx) : 0.f;
    sm[t] = ex;
    __syncthreads();
    for (int s = 128; s > 0; s >>= 1) {
        if (t < s) sm[t] += sm[t + s];
        __syncthreads();
    }
    float inv = 1.f / sm[0];
    if (t < N_) a_out[(size_t)b * N_ + t] = ex * inv;
}

__global__ void k_ctx_f32(const float* __restrict__ V, const float* __restrict__ a,
                          float* __restrict__ ctx) {
    int b  = blockIdx.x;
    int ch = blockIdx.y;
    int t  = threadIdx.x;  // 128
    __shared__ float as_[N_];
    for (int i = t; i < N_; i += 128) as_[i] = a[(size_t)b * N_ + i];
    __syncthreads();
    int col = ch * 512 + t * 4;
    const f32x4* Vp = reinterpret_cast<const f32x4*>(V + (size_t)b * N_ * VDIM + col);
    f32x4 accv = {0.f, 0.f, 0.f, 0.f};
    for (int n = 0; n < N_; ++n)
        accv += as_[n] * Vp[(size_t)n * (VDIM / 4)];
    *reinterpret_cast<f32x4*>(ctx + (size_t)b * VDIM + col) = accv;
}

// ---------------------------------------------------------------------------
extern "C" void kernel_launch(void* const* d_in, const int* in_sizes, int n_in,
                              void* d_out, int out_size, void* d_ws, size_t ws_size,
                              hipStream_t stream) {
    const float* h  = (const float*)d_in[0];
    const float* V  = (const float*)d_in[1];
    const float* Ww = (const float*)d_in[2];
    const float* Wb = (const float*)d_in[3];
    const float* Uw = (const float*)d_in[4];
    const float* Ub = (const float*)d_in[5];
    const float* vw = (const float*)d_in[6];
    const float* vb = (const float*)d_in[7];

    float* out     = (float*)d_out;
    float* ctx_out = out;                        // B*VDIM floats
    float* a_out   = out + (size_t)B_ * VDIM;    // B*N floats

    const size_t vb_bytes = (size_t)B_ * N_ * VDIM * sizeof(__bf16);  // ~103 MB
    const size_t tail     = 2u * 1024 * 1024 + 256 * 1024 + (size_t)4 * M_TOT * 4 + 4096;
    bool preconv = ws_size >= vb_bytes + tail;

    char*   ws   = (char*)d_ws;
    __bf16* Vb   = (__bf16*)ws;
    char*   rest = ws + (preconv ? vb_bytes : 0);
    __bf16* UwT   = (__bf16*)rest;
    float*  whp   = (float*)(rest + 2u * 1024 * 1024);
    float*  e_prt = (float*)(rest + 2u * 1024 * 1024 + 256 * 1024);

    int grid_cp = preconv ? (384 + NCONVB) : 384;
    k_convprep<<<dim3(grid_cp), 256, 0, stream>>>(
        V, Vb, Uw, UwT, h, Ww, Wb, Ub, whp);
    if (preconv) {
        k_scores128<<<dim3(784), 256, 0, stream>>>(Vb, UwT, whp, vw, e_prt);
        k_ctx_sm<<<dim3(B_, 2), 256, 0, stream>>>(Vb, e_prt, vb, a_out, ctx_out);
    } else {
        k_scores_small<<<dim3(784), 256, 0, stream>>>(V, UwT, whp, vw, e_prt);
        k_softmax<<<dim3(B_), 256, 0, stream>>>(e_prt, vb, a_out);
        k_ctx_f32<<<dim3(B_, 4), 128, 0, stream>>>(V, a_out, ctx_out);
    }
}

// Round 15
// 142.840 us; speedup vs baseline: 1.1222x; 1.0456x over previous
//
#include <hip/hip_runtime.h>
#include <hip/hip_bf16.h>

#define B_    128
#define N_    196
#define HDIM  512
#define VDIM  2048
#define ATT   512
#define M_TOT (B_ * N_)   // 25088

#define BKK 64             // K step (64 bf16 = 128B = 8 chunks of 16B)
#define NT  (VDIM / BKK)   // 32 K-steps
#define BM1 128
#define BN1 128
#define BM2 256
#define BN2 256
#define N8     ((B_ * N_ * VDIM) / 8)   // 6,422,528 float8 items
#define NCONVB 12544                     // conv blocks; 2 items each (TLP)

typedef float  f32x4  __attribute__((ext_vector_type(4)));
typedef __bf16 bf16x8 __attribute__((ext_vector_type(8)));
typedef __bf16 bf16x4 __attribute__((ext_vector_type(4)));

__device__ __forceinline__ void gload_lds16(const void* g, void* l) {
    __builtin_amdgcn_global_load_lds(
        (const __attribute__((address_space(1))) void*)g,
        (__attribute__((address_space(3))) void*)l, 16, 0, 0);
}

__device__ __forceinline__ float fast_tanh(float x) {
    float ax = fabsf(x);
    float e  = __expf(-2.f * ax);          // in (0,1], no overflow
    float t  = (1.f - e) / (1.f + e);
    return copysignf(t, x);
}

// ---------------------------------------------------------------------------
// Kernel CP (merged): [R14-verified]
//   [0,128):           whp = h@Ww + Wb + Ub   (unroll-8)
//   [128,384):         Uw transpose -> UwT bf16
//   [384,384+NCONVB):  V fp32 -> bf16; 2 items/thread, TLP via 12544 blocks
// ---------------------------------------------------------------------------
__global__ void k_convprep(const float* __restrict__ V, __bf16* __restrict__ Vb,
                           const float* __restrict__ Uw, __bf16* __restrict__ UwT,
                           const float* __restrict__ h, const float* __restrict__ Ww,
                           const float* __restrict__ Wb, const float* __restrict__ Ub,
                           float* __restrict__ whp) {
    int t = threadIdx.x;  // 256
    if (blockIdx.x < 128) {
        __shared__ float hs[HDIM];
        int b = blockIdx.x;
        hs[t]       = h[(size_t)b * HDIM + t];
        hs[t + 256] = h[(size_t)b * HDIM + t + 256];
        __syncthreads();
        float a0[8] = {0,0,0,0,0,0,0,0}, a1[8] = {0,0,0,0,0,0,0,0};
        for (int k0 = 0; k0 < HDIM; k0 += 8) {
#pragma unroll
            for (int u = 0; u < 8; ++u) {
                float hv = hs[k0 + u];
                a0[u] += hv * Ww[(size_t)(k0 + u) * ATT + t];
                a1[u] += hv * Ww[(size_t)(k0 + u) * ATT + t + 256];
            }
        }
        float s0 = ((a0[0] + a0[1]) + (a0[2] + a0[3])) + ((a0[4] + a0[5]) + (a0[6] + a0[7]));
        float s1 = ((a1[0] + a1[1]) + (a1[2] + a1[3])) + ((a1[4] + a1[5]) + (a1[6] + a1[7]));
        whp[(size_t)b * ATT + t]       = s0 + Wb[t] + Ub[t];
        whp[(size_t)b * ATT + t + 256] = s1 + Wb[t + 256] + Ub[t + 256];
    } else if (blockIdx.x < 384) {
        __shared__ __bf16 st[64][65];
        int bb = blockIdx.x - 128;
        int k0 = (bb & 31) * 64;
        int c0 = (bb >> 5) * 64;
#pragma unroll
        for (int i = 0; i < 16; ++i) {
            int lin = i * 256 + t;
            int kk = lin >> 6, cc = lin & 63;
            st[kk][cc] = (__bf16)Uw[(size_t)(k0 + kk) * ATT + c0 + cc];
        }
        __syncthreads();
#pragma unroll
        for (int i = 0; i < 16; ++i) {
            int lin = i * 256 + t;
            int cc = lin >> 6, kk = lin & 63;
            UwT[(size_t)(c0 + cc) * VDIM + k0 + kk] = st[kk][cc];
        }
    } else {
        size_t base = (size_t)(blockIdx.x - 384) * 256 + t;
        const float4* Vp = reinterpret_cast<const float4*>(V);
        float4 xs[2], ys[2];
#pragma unroll
        for (int u = 0; u < 2; ++u) {
            size_t i = base + (size_t)u * ((size_t)NCONVB * 256);
            xs[u] = Vp[2 * i];
            ys[u] = Vp[2 * i + 1];
        }
#pragma unroll
        for (int u = 0; u < 2; ++u) {
            size_t i = base + (size_t)u * ((size_t)NCONVB * 256);
            float4 x = xs[u], y = ys[u];
            bf16x8 w;
            w[0] = (__bf16)x.x; w[1] = (__bf16)x.y; w[2] = (__bf16)x.z; w[3] = (__bf16)x.w;
            w[4] = (__bf16)y.x; w[5] = (__bf16)y.y; w[6] = (__bf16)y.z; w[7] = (__bf16)y.w;
            reinterpret_cast<bf16x8*>(Vb)[i] = w;
        }
    }
}

// ---------------------------------------------------------------------------
// Kernel G (main): 256x256 tile, 8 waves (2 row-halves x 4 col-quarters),
// counted-vmcnt depth-2 pipeline (R7-verified sync on R5-verified geometry).
// Both operands via global_load_lds, XOR-swizzled (pre-swizzled source,
// linear dest, swizzled ds_read). Grid 196 (XCD-bijective), 1 block/CU.
// Epilogue: e_part[cc][m] = sum over this block's 256 cols.
// ---------------------------------------------------------------------------
__global__ __launch_bounds__(512, 2) void k_scores256(
    const __bf16* __restrict__ Vb, const __bf16* __restrict__ UwT,
    const float* __restrict__ whp, const float* __restrict__ vw,
    float* __restrict__ e_part)
{
    __shared__ __align__(16) __bf16 As[2][BM2][BKK];   // 64 KB
    __shared__ __align__(16) __bf16 Bs[2][BN2][BKK];   // 64 KB
    __shared__ float red[4][BM2];                      // 4 KB

    // bijective XCD swizzle for 196 blocks (m204: q=24, r=4)
    int bid = blockIdx.x;
    int xcd = bid & 7, ix = bid >> 3;
    int lid = (xcd < 4 ? xcd * 25 : 100 + (xcd - 4) * 24) + ix;
    int mtile = lid >> 1;         // 0..97
    int cc    = lid & 1;          // 0..1
    int m0 = mtile * BM2;
    int c0 = cc * BN2;

    int t    = threadIdx.x;       // 0..511
    int lane = t & 63;
    int wave = t >> 6;            // 0..7
    int wr = wave >> 2;           // 0..1 : row half (128 rows)
    int wc = wave & 3;            // 0..3 : col quarter (64 cols)

    f32x4 acc[8][4];
#pragma unroll
    for (int i = 0; i < 8; ++i)
#pragma unroll
        for (int j = 0; j < 4; ++j) acc[i][j] = (f32x4){0.f, 0.f, 0.f, 0.f};

    // staging: wave w instr i covers rows [w*32 + i*8, +8); lane -> (lr, chunk).
    // LDS[r][c] holds global chunk c^(r&7); dest linear -> source chunk (lane&7)^lr.
    int lr  = lane >> 3;                       // 0..7
    int csw = ((lane & 7) ^ lr) * 8;           // pre-swizzled source elems
    const __bf16* AgS = Vb  + (size_t)(m0 + wave * 32 + lr) * VDIM + csw;
    const __bf16* BgS = UwT + (size_t)(c0 + wave * 32 + lr) * VDIM + csw;
    __bf16* Al0 = &As[0][wave * 32 + lr][(lane & 7) * 8];
    __bf16* Bl0 = &Bs[0][wave * 32 + lr][(lane & 7) * 8];

    // 8 gload_lds per STAGE per thread (4 A + 4 B) -> vmcnt(8) = one STAGE
#define STAGE2(buf, kt)                                                         \
    do {                                                                        \
        _Pragma("unroll")                                                       \
        for (int i = 0; i < 4; ++i) {                                           \
            gload_lds16(AgS + (kt) * BKK + (size_t)i * 8 * VDIM,                \
                        Al0 + (buf) * (BM2 * BKK) + i * 8 * BKK);               \
            gload_lds16(BgS + (kt) * BKK + (size_t)i * 8 * VDIM,                \
                        Bl0 + (buf) * (BN2 * BKK) + i * 8 * BKK);               \
        }                                                                       \
    } while (0)

    int lcol = lane & 15;
    int lg4  = lane >> 4;
    int arow0 = wr * 128;
    int bcol0 = wc * 64;

    STAGE2(0, 0);
    __builtin_amdgcn_sched_barrier(0);   // pin issue order: tile0 before tile1
    STAGE2(1, 1);

    for (int kt = 0; kt < NT; ++kt) {
        int buf = kt & 1;
        if (kt < NT - 1) {
            asm volatile("s_waitcnt vmcnt(8)\n\ts_barrier" ::: "memory");
        } else {
            asm volatile("s_waitcnt vmcnt(0)\n\ts_barrier" ::: "memory");
        }
        __builtin_amdgcn_sched_barrier(0);

#pragma unroll
        for (int ks = 0; ks < 2; ++ks) {
            bf16x8 bfr[4], af[8];
#pragma unroll
            for (int j = 0; j < 4; ++j) {
                int row = bcol0 + j * 16 + lcol;
                int ch  = ((ks * 4 + lg4) ^ (row & 7)) * 8;
                bfr[j] = *reinterpret_cast<const bf16x8*>(&Bs[buf][row][ch]);
            }
#pragma unroll
            for (int i = 0; i < 8; ++i) {
                int row = arow0 + i * 16 + lcol;
                int ch  = ((ks * 4 + lg4) ^ (row & 7)) * 8;
                af[i] = *reinterpret_cast<const bf16x8*>(&As[buf][row][ch]);
            }
            __builtin_amdgcn_s_setprio(1);
#pragma unroll
            for (int i = 0; i < 8; ++i)
#pragma unroll
                for (int j = 0; j < 4; ++j)
                    acc[i][j] = __builtin_amdgcn_mfma_f32_16x16x32_bf16(af[i], bfr[j], acc[i][j], 0, 0, 0);
            __builtin_amdgcn_s_setprio(0);
        }

        __builtin_amdgcn_sched_barrier(0);
        asm volatile("s_barrier" ::: "memory");   // buf free: all waves consumed it
        if (kt + 2 < NT) STAGE2(buf, kt + 2);
    }
#undef STAGE2

    // ---- epilogue: rowsum over this block's 256 cols ----
    int lrow4 = lg4 * 4;
#pragma unroll
    for (int i = 0; i < 8; ++i) {
        float rs[4] = {0.f, 0.f, 0.f, 0.f};
#pragma unroll
        for (int j = 0; j < 4; ++j) {
            int col = c0 + wc * 64 + j * 16 + lcol;
            float vwv = vw[col];
#pragma unroll
            for (int r = 0; r < 4; ++r) {
                int m = m0 + wr * 128 + i * 16 + lrow4 + r;
                int b = m / N_;
                float x = acc[i][j][r] + whp[(size_t)b * ATT + col];
                rs[r] += fast_tanh(x) * vwv;
            }
        }
#pragma unroll
        for (int r = 0; r < 4; ++r) {
            float v = rs[r];
            v += __shfl_xor(v, 1);
            v += __shfl_xor(v, 2);
            v += __shfl_xor(v, 4);
            v += __shfl_xor(v, 8);
            if (lcol == 0)
                red[wc][wr * 128 + i * 16 + lrow4 + r] = v;
        }
    }
    __syncthreads();
    if (t < BM2)
        e_part[(size_t)cc * M_TOT + m0 + t] =
            red[0][t] + red[1][t] + red[2][t] + red[3][t];
}

// ---------------------------------------------------------------------------
// Kernel G (fallback, no-ws path): 128x128, fp32 A reg-staged (R3-proven).
// ---------------------------------------------------------------------------
__global__ __launch_bounds__(256, 2) void k_scores_small(
    const float* __restrict__ Vf, const __bf16* __restrict__ UwT,
    const float* __restrict__ whp, const float* __restrict__ vw,
    float* __restrict__ e_part)
{
    __shared__ __align__(16) __bf16 As[2][BM1][BKK];
    __shared__ __align__(16) __bf16 Bs[2][BN1][BKK];
    __shared__ float red[2][BM1];

    int bid = blockIdx.x;
    int lid = (bid & 7) * (784 / 8) + (bid >> 3);
    int mtile = lid >> 2;
    int cc    = lid & 3;
    int m0 = mtile * BM1;
    int c0 = cc * BN1;
    int t    = threadIdx.x;
    int lane = t & 63;
    int wave = t >> 6;
    int wr = wave >> 1;
    int wc = wave & 1;

    f32x4 acc[4][4];
#pragma unroll
    for (int i = 0; i < 4; ++i)
#pragma unroll
        for (int j = 0; j < 4; ++j) acc[i][j] = (f32x4){0.f, 0.f, 0.f, 0.f};

    int lr  = lane >> 3;
    int csw = ((lane & 7) ^ lr) * 8;
    const __bf16* BgS = UwT + (size_t)(c0 + wave * 32 + lr) * VDIM + csw;
    __bf16* Bl0 = &Bs[0][wave * 32 + lr][(lane & 7) * 8];

    int ra = t >> 1;
    int ka = (t & 1) * 32;
    const float* Af = Vf + (size_t)(m0 + ra) * VDIM + ka;

#define STAGE1(buf, kt)                                                         \
    do {                                                                        \
        _Pragma("unroll")                                                       \
        for (int i = 0; i < 4; ++i)                                             \
            gload_lds16(BgS + (kt) * BKK + (size_t)i * 8 * VDIM,                \
                        Bl0 + (buf) * (BN1 * BKK) + i * 8 * BKK);               \
        const float4* src = reinterpret_cast<const float4*>(Af + (kt) * BKK);   \
        _Pragma("unroll")                                                       \
        for (int i = 0; i < 4; ++i) {                                           \
            float4 x = src[2 * i];                                              \
            float4 y = src[2 * i + 1];                                          \
            bf16x8 w;                                                           \
            w[0] = (__bf16)x.x; w[1] = (__bf16)x.y;                             \
            w[2] = (__bf16)x.z; w[3] = (__bf16)x.w;                             \
            w[4] = (__bf16)y.x; w[5] = (__bf16)y.y;                             \
            w[6] = (__bf16)y.z; w[7] = (__bf16)y.w;                             \
            int ch = (((t & 1) * 4 + i) ^ (ra & 7)) * 8;                        \
            *reinterpret_cast<bf16x8*>(&As[buf][ra][ch]) = w;                   \
        }                                                                       \
    } while (0)

    int lcol = lane & 15;
    int lg4  = lane >> 4;
    int arow0 = wr * 64;
    int bcol0 = wc * 64;

    STAGE1(0, 0);
    __syncthreads();

    for (int kt = 0; kt < NT; ++kt) {
        int buf = kt & 1;
        if (kt + 1 < NT) STAGE1(buf ^ 1, kt + 1);
#pragma unroll
        for (int ks = 0; ks < 2; ++ks) {
            bf16x8 af[4], bfr[4];
#pragma unroll
            for (int i = 0; i < 4; ++i) {
                int row = arow0 + i * 16 + lcol;
                int ch  = ((ks * 4 + lg4) ^ (row & 7)) * 8;
                af[i] = *reinterpret_cast<const bf16x8*>(&As[buf][row][ch]);
            }
#pragma unroll
            for (int j = 0; j < 4; ++j) {
                int row = bcol0 + j * 16 + lcol;
                int ch  = ((ks * 4 + lg4) ^ (row & 7)) * 8;
                bfr[j] = *reinterpret_cast<const bf16x8*>(&Bs[buf][row][ch]);
            }
#pragma unroll
            for (int i = 0; i < 4; ++i)
#pragma unroll
                for (int j = 0; j < 4; ++j)
                    acc[i][j] = __builtin_amdgcn_mfma_f32_16x16x32_bf16(af[i], bfr[j], acc[i][j], 0, 0, 0);
        }
        __syncthreads();
    }
#undef STAGE1

    int lrow4 = lg4 * 4;
#pragma unroll
    for (int i = 0; i < 4; ++i) {
        float rs[4] = {0.f, 0.f, 0.f, 0.f};
#pragma unroll
        for (int j = 0; j < 4; ++j) {
            int col = c0 + wc * 64 + j * 16 + lcol;
            float vwv = vw[col];
#pragma unroll
            for (int r = 0; r < 4; ++r) {
                int m = m0 + wr * 64 + i * 16 + lrow4 + r;
                int b = m / N_;
                float x = acc[i][j][r] + whp[(size_t)b * ATT + col];
                rs[r] += fast_tanh(x) * vwv;
            }
        }
#pragma unroll
        for (int r = 0; r < 4; ++r) {
            float v = rs[r];
            v += __shfl_xor(v, 1);
            v += __shfl_xor(v, 2);
            v += __shfl_xor(v, 4);
            v += __shfl_xor(v, 8);
            if (lcol == 0)
                red[wc][wr * 64 + i * 16 + lrow4 + r] = v;
        }
    }
    __syncthreads();
    if (t < BM1)
        e_part[(size_t)cc * M_TOT + m0 + t] = red[0][t] + red[1][t];
}

// ---------------------------------------------------------------------------
// Kernel CS (fused softmax + ctx, bf16 V): 256 threads. npart partials.
// Both (b,ch) blocks recompute identical softmax (deterministic); ch==0
// writes a_out; each accumulates 1024 ctx cols (4 cols/thread).
// ---------------------------------------------------------------------------
__global__ void k_ctx_sm(const __bf16* __restrict__ Vb, const float* __restrict__ e_part,
                         const float* __restrict__ vb, float* __restrict__ a_out,
                         float* __restrict__ ctx, int npart) {
    int b  = blockIdx.x;   // 128
    int ch = blockIdx.y;   // 2 chunks of 1024 cols
    int t  = threadIdx.x;  // 256
    __shared__ float sm[256];
    __shared__ float as_[N_];

    float ev = 0.f;
    float e  = -1e30f;
    if (t < N_) {
        int m = b * N_ + t;
        ev = vb[0];
        for (int p = 0; p < npart; ++p) ev += e_part[(size_t)p * M_TOT + m];
        e = ev;
    }
    sm[t] = e;
    __syncthreads();
    for (int s = 128; s > 0; s >>= 1) {
        if (t < s) sm[t] = fmaxf(sm[t], sm[t + s]);
        __syncthreads();
    }
    float mx = sm[0];
    __syncthreads();
    float ex = (t < N_) ? __expf(ev - mx) : 0.f;
    sm[t] = ex;
    __syncthreads();
    for (int s = 128; s > 0; s >>= 1) {
        if (t < s) sm[t] += sm[t + s];
        __syncthreads();
    }
    float inv = 1.f / sm[0];
    if (t < N_) {
        as_[t] = ex * inv;
        if (ch == 0) a_out[(size_t)b * N_ + t] = ex * inv;
    }
    __syncthreads();

    int col = ch * 1024 + t * 4;
    const __bf16* Vp = Vb + (size_t)b * N_ * VDIM + col;
    float av[4] = {0.f, 0.f, 0.f, 0.f};
    for (int n = 0; n < N_; ++n) {
        bf16x4 v = *reinterpret_cast<const bf16x4*>(Vp + (size_t)n * VDIM);
        float an = as_[n];
#pragma unroll
        for (int j = 0; j < 4; ++j) av[j] += an * (float)v[j];
    }
    f32x4 o = {av[0], av[1], av[2], av[3]};
    *reinterpret_cast<f32x4*>(ctx + (size_t)b * VDIM + col) = o;
}

// ---------------------------------------------------------------------------
// Fallback softmax + fp32 ctx (no-ws path)
// ---------------------------------------------------------------------------
__global__ void k_softmax(const float* __restrict__ e_part, const float* __restrict__ vb,
                          float* __restrict__ a_out) {
    int b = blockIdx.x;
    int t = threadIdx.x;  // 256
    __shared__ float sm[256];
    float ev = 0.f;
    float e  = -1e30f;
    if (t < N_) {
        int m = b * N_ + t;
        ev = e_part[m] + e_part[M_TOT + m] + e_part[2 * M_TOT + m] + e_part[3 * M_TOT + m] + vb[0];
        e = ev;
    }
    sm[t] = e;
    __syncthreads();
    for (int s = 128; s > 0; s >>= 1) {
        if (t < s) sm[t] = fmaxf(sm[t], sm[t + s]);
        __syncthreads();
    }
    float mx = sm[0];
    __syncthreads();
    float ex = (t < N_) ? __expf(ev - mx) : 0.f;
    sm[t] = ex;
    __syncthreads();
    for (int s = 128; s > 0; s >>= 1) {
        if (t < s) sm[t] += sm[t + s];
        __syncthreads();
    }
    float inv = 1.f / sm[0];
    if (t < N_) a_out[(size_t)b * N_ + t] = ex * inv;
}

__global__ void k_ctx_f32(const float* __restrict__ V, const float* __restrict__ a,
                          float* __restrict__ ctx) {
    int b  = blockIdx.x;
    int ch = blockIdx.y;
    int t  = threadIdx.x;  // 128
    __shared__ float as_[N_];
    for (int i = t; i < N_; i += 128) as_[i] = a[(size_t)b * N_ + i];
    __syncthreads();
    int col = ch * 512 + t * 4;
    const f32x4* Vp = reinterpret_cast<const f32x4*>(V + (size_t)b * N_ * VDIM + col);
    f32x4 accv = {0.f, 0.f, 0.f, 0.f};
    for (int n = 0; n < N_; ++n)
        accv += as_[n] * Vp[(size_t)n * (VDIM / 4)];
    *reinterpret_cast<f32x4*>(ctx + (size_t)b * VDIM + col) = accv;
}

// ---------------------------------------------------------------------------
extern "C" void kernel_launch(void* const* d_in, const int* in_sizes, int n_in,
                              void* d_out, int out_size, void* d_ws, size_t ws_size,
                              hipStream_t stream) {
    const float* h  = (const float*)d_in[0];
    const float* V  = (const float*)d_in[1];
    const float* Ww = (const float*)d_in[2];
    const float* Wb = (const float*)d_in[3];
    const float* Uw = (const float*)d_in[4];
    const float* Ub = (const float*)d_in[5];
    const float* vw = (const float*)d_in[6];
    const float* vb = (const float*)d_in[7];

    float* out     = (float*)d_out;
    float* ctx_out = out;                        // B*VDIM floats
    float* a_out   = out + (size_t)B_ * VDIM;    // B*N floats

    const size_t vb_bytes = (size_t)B_ * N_ * VDIM * sizeof(__bf16);  // ~103 MB
    const size_t tail     = 2u * 1024 * 1024 + 256 * 1024 + (size_t)4 * M_TOT * 4 + 4096;
    bool preconv = ws_size >= vb_bytes + tail;

    char*   ws   = (char*)d_ws;
    __bf16* Vb   = (__bf16*)ws;
    char*   rest = ws + (preconv ? vb_bytes : 0);
    __bf16* UwT   = (__bf16*)rest;
    float*  whp   = (float*)(rest + 2u * 1024 * 1024);
    float*  e_prt = (float*)(rest + 2u * 1024 * 1024 + 256 * 1024);

    int grid_cp = preconv ? (384 + NCONVB) : 384;
    k_convprep<<<dim3(grid_cp), 256, 0, stream>>>(
        V, Vb, Uw, UwT, h, Ww, Wb, Ub, whp);
    if (preconv) {
        k_scores256<<<dim3(196), 512, 0, stream>>>(Vb, UwT, whp, vw, e_prt);
        k_ctx_sm<<<dim3(B_, 2), 256, 0, stream>>>(Vb, e_prt, vb, a_out, ctx_out, 2);
    } else {
        k_scores_small<<<dim3(784), 256, 0, stream>>>(V, UwT, whp, vw, e_prt);
        k_softmax<<<dim3(B_), 256, 0, stream>>>(e_prt, vb, a_out);
        k_ctx_f32<<<dim3(B_, 4), 128, 0, stream>>>(V, a_out, ctx_out);
    }
}